// Round 3
// baseline (211.353 us; speedup 1.0000x reference)
//
#include <hip/hip_runtime.h>
#include <hip/hip_fp16.h>

// Problem constants
#define NV   20000
#define KK   3
#define INF  150
#define HH   64
#define OO   128
#define PT   80
#define KTOT 5120     // 80 bins * 64 h
#define NB   32       // vertices per geo block
#define BS   72       // per-bin stride in pch, halves (64 + 8 pad)
#define RS   584      // pch row stride = 8*BS + 8 halves (1168 B; 292 words % 32 == 4)
#define XS   168      // x/W1 LDS col stride, halves (84 words % 32 == 20 -> 2-way free)

typedef _Float16 fh8 __attribute__((ext_vector_type(8)));   // MFMA A/B frag (4 VGPRs)
typedef __attribute__((ext_vector_type(4))) float f32x4;    // MFMA C/D frag

__device__ __forceinline__ unsigned short f2h(float f) {
    return __half_as_ushort(__float2half(f));
}

// ---------------------------------------------------------------------------
// Repack Wg [O][H][P][T] fp32 -> W2 [S=k/32][o][kk] fp16, k = bin*64 + h.
// B-frag for (k-step S, o-tile) is then one contiguous 1KB wave load.
// ---------------------------------------------------------------------------
__global__ void prep_w2_kernel(const float* __restrict__ Wg,
                               unsigned short* __restrict__ W2) {
    int e  = blockIdx.x * 256 + threadIdx.x;      // 655360 = 2560*256 exact
    int S  = e >> 12;
    int o  = (e >> 5) & 127;
    int kk = e & 31;
    int k  = S * 32 + kk;
    W2[e] = f2h(Wg[o * KTOT + (k & 63) * PT + (k >> 6)]);
}

// ---------------------------------------------------------------------------
// h = relu(x @ W1^T) -> fp16 [N][64], via MFMA. 32 rows/block, grid 625.
// x and W1 staged to LDS as fp16 (stride 168 halves: 2-way banks, free).
// Wave wv: o-tile = wv; m-tiles {0,1}. 5 k-steps of 32 (K=150 zero-padded).
// ---------------------------------------------------------------------------
__global__ __launch_bounds__(256) void linear_relu_kernel(
    const float* __restrict__ x, const float* __restrict__ W1,
    unsigned short* __restrict__ hb) {
    __shared__ __align__(16) unsigned short xs[32 * XS];
    __shared__ __align__(16) unsigned short ws[64 * XS];
    const int tid = threadIdx.x;
    const int n0  = blockIdx.x * 32;

    for (int e = tid; e < 32 * INF; e += 256) {
        int r = e / INF, c = e - r * INF;
        xs[r * XS + c] = f2h(x[n0 * INF + e]);
    }
    for (int e = tid; e < 32 * 18; e += 256) {    // zero cols 150..167
        int r = e / 18, c = e - r * 18;
        xs[r * XS + 150 + c] = 0;
    }
    for (int e = tid; e < 64 * INF; e += 256) {
        int r = e / INF, c = e - r * INF;
        ws[r * XS + c] = f2h(W1[e]);
    }
    for (int e = tid; e < 64 * 18; e += 256) {
        int r = e / 18, c = e - r * 18;
        ws[r * XS + 150 + c] = 0;
    }
    __syncthreads();

    const int wv   = tid >> 6;
    const int lane = tid & 63;
    const int q    = lane >> 4;
    const int r16  = lane & 15;
    const int o0   = wv * 16;

    f32x4 acc0 = {0.f, 0.f, 0.f, 0.f};
    f32x4 acc1 = acc0;
    #pragma unroll
    for (int s = 0; s < 5; s++) {
        const int kb = s * 32 + q * 8;
        fh8 a0 = *(const fh8*)(xs + r16 * XS + kb);
        fh8 a1 = *(const fh8*)(xs + (16 + r16) * XS + kb);
        fh8 b  = *(const fh8*)(ws + (o0 + r16) * XS + kb);
        acc0 = __builtin_amdgcn_mfma_f32_16x16x32_f16(a0, b, acc0, 0, 0, 0);
        acc1 = __builtin_amdgcn_mfma_f32_16x16x32_f16(a1, b, acc1, 0, 0, 0);
    }
    // D layout: row = q*4+r (n within tile), col = r16 (o within tile)
    #pragma unroll
    for (int r = 0; r < 4; r++) {
        float v0 = acc0[r] > 0.f ? acc0[r] : 0.f;
        float v1 = acc1[r] > 0.f ? acc1[r] : 0.f;
        hb[(n0 + q * 4 + r) * HH + o0 + r16]      = f2h(v0);
        hb[(n0 + 16 + q * 4 + r) * HH + o0 + r16] = f2h(v1);
    }
}

// ---------------------------------------------------------------------------
// Fused gather + fp16 MFMA contraction + bias + L2 normalize.
// 256 thr = 4 waves, 32 vertices/block. 10 chunks of 8 bins.
// Gather reads conn directly from global (8 lanes share one 24B group),
// combines 3 h-rows with v_pk_fma_f16, writes fp16 patches to LDS.
// MFMA: wave wv owns o-tiles {2wv,2wv+1} x m-tiles {0,1}.
// LDS 37.6 KB -> 4 blocks/CU.
// ---------------------------------------------------------------------------
__global__ __launch_bounds__(256, 4) void geo_kernel(
    const int*   __restrict__ conn_idx, const float* __restrict__ conn_w,
    const unsigned short* __restrict__ W2, const unsigned short* __restrict__ hb,
    const float* __restrict__ bg, float* __restrict__ out) {
    __shared__ __align__(16) unsigned short pch[NB * RS];  // 37376 B; aliased as outbuf
    __shared__ float rsq[NB];
    float* outbuf = (float*)pch;                 // 32*132*4 = 16896 B <= 37376 B

    const int tid  = threadIdx.x;
    const int n0   = blockIdx.x * NB;
    const int wv   = tid >> 6;
    const int lane = tid & 63;
    const int q    = lane >> 4;
    const int r16  = lane & 15;
    const int j8   = tid & 7;                    // 16B sub-segment of h row
    const int bb   = (tid >> 3) & 7;             // bin within chunk

    f32x4 acc00 = {0.f, 0.f, 0.f, 0.f};
    f32x4 acc01 = acc00, acc10 = acc00, acc11 = acc00;

    for (int cc = 0; cc < 10; cc++) {
        __syncthreads();                         // prev MFMA phase done with pch
        #pragma unroll
        for (int i = 0; i < 8; i++) {
            const int n = i * 4 + wv;            // vertex row this wave handles
            const int g = (n0 + n) * (PT * KK) + (cc * 8 + bb) * KK;
            int   i0 = conn_idx[g],     i1 = conn_idx[g + 1], i2 = conn_idx[g + 2];
            float f0 = conn_w[g],       f1 = conn_w[g + 1],   f2 = conn_w[g + 2];
            fh8 h0 = *(const fh8*)(hb + i0 * HH + j8 * 8);
            fh8 h1 = *(const fh8*)(hb + i1 * HH + j8 * 8);
            fh8 h2 = *(const fh8*)(hb + i2 * HH + j8 * 8);
            _Float16 w0 = (_Float16)f0, w1 = (_Float16)f1, w2 = (_Float16)f2;
            fh8 W0 = {w0, w0, w0, w0, w0, w0, w0, w0};
            fh8 W1v = {w1, w1, w1, w1, w1, w1, w1, w1};
            fh8 W2v = {w2, w2, w2, w2, w2, w2, w2, w2};
            fh8 r = h0 * W0 + h1 * W1v + h2 * W2v;     // v_pk_fma_f16 x12
            *(fh8*)(pch + n * RS + bb * BS + j8 * 8) = r;
        }
        __syncthreads();
        #pragma unroll
        for (int s = 0; s < 16; s++) {
            const int S  = cc * 16 + s;
            const int b  = s >> 1, hf = s & 1;
            const int ao = b * BS + hf * 32 + q * 8;
            fh8 a0 = *(const fh8*)(pch + r16 * RS + ao);
            fh8 a1 = *(const fh8*)(pch + (16 + r16) * RS + ao);
            fh8 b0 = *(const fh8*)(W2 + S * 4096 + ((wv * 2 + 0) * 16 + r16) * 32 + q * 8);
            fh8 b1 = *(const fh8*)(W2 + S * 4096 + ((wv * 2 + 1) * 16 + r16) * 32 + q * 8);
            acc00 = __builtin_amdgcn_mfma_f32_16x16x32_f16(a0, b0, acc00, 0, 0, 0);
            acc01 = __builtin_amdgcn_mfma_f32_16x16x32_f16(a0, b1, acc01, 0, 0, 0);
            acc10 = __builtin_amdgcn_mfma_f32_16x16x32_f16(a1, b0, acc10, 0, 0, 0);
            acc11 = __builtin_amdgcn_mfma_f32_16x16x32_f16(a1, b1, acc11, 0, 0, 0);
        }
    }

    __syncthreads();                             // done with pch; alias as outbuf
    {   // D layout: row = q*4+reg (vertex in tile), col = r16 (o in tile)
        const int o0 = wv * 32;
        #pragma unroll
        for (int r = 0; r < 4; r++) {
            outbuf[(q * 4 + r) * 132 + o0 + r16]           = acc00[r];
            outbuf[(q * 4 + r) * 132 + o0 + 16 + r16]      = acc01[r];
            outbuf[(16 + q * 4 + r) * 132 + o0 + r16]      = acc10[r];
            outbuf[(16 + q * 4 + r) * 132 + o0 + 16 + r16] = acc11[r];
        }
    }
    __syncthreads();
    {   // bias + row L2 norm
        int rr = tid >> 3, l = tid & 7;
        float s = 0.f;
        for (int o = l; o < 128; o += 8) {
            float v = outbuf[rr * 132 + o] + bg[o];
            s += v * v;
        }
        for (int off = 4; off; off >>= 1) s += __shfl_down(s, off, 8);
        if (l == 0) rsq[rr] = rsqrtf(s);
    }
    __syncthreads();
    #pragma unroll
    for (int i = 0; i < 16; i++) {
        int e = i * 256 + tid;
        int n = e >> 7, o = e & 127;
        out[(n0 + n) * OO + o] = (outbuf[n * 132 + o] + bg[o]) * rsq[n];
    }
}

// ---------------------------------------------------------------------------
extern "C" void kernel_launch(void* const* d_in, const int* in_sizes, int n_in,
                              void* d_out, int out_size, void* d_ws, size_t ws_size,
                              hipStream_t stream) {
    const float* x        = (const float*)d_in[0];
    const int*   conn_idx = (const int*)  d_in[1];
    const float* conn_w   = (const float*)d_in[2];
    const float* W1       = (const float*)d_in[3];
    const float* Wg       = (const float*)d_in[4];
    const float* bg       = (const float*)d_in[5];
    float*       out      = (float*)d_out;

    unsigned short* W2 = (unsigned short*)d_ws;            // 655360 fp16 (1.31 MB)
    unsigned short* hb = W2 + OO * KTOT;                   // 1,280,000 fp16 (2.56 MB)

    hipLaunchKernelGGL(prep_w2_kernel, dim3(2560), dim3(256), 0, stream, Wg, W2);
    hipLaunchKernelGGL(linear_relu_kernel, dim3(NV / 32), dim3(256), 0, stream, x, W1, hb);
    hipLaunchKernelGGL(geo_kernel, dim3(NV / NB), dim3(256), 0, stream,
                       conn_idx, conn_w, W2, hb, bg, out);
}

// Round 4
// 195.418 us; speedup vs baseline: 1.0815x; 1.0815x over previous
//
#include <hip/hip_runtime.h>
#include <hip/hip_fp16.h>

// Problem constants
#define NV   20000
#define KK   3
#define INF  150
#define HH   64
#define OO   128
#define PT   80
#define KTOT 5120      // 80 bins * 64 h
#define NB   32        // vertices per geo block
#define BS   72        // per-bin stride in pch, halves (64 + 8 pad)
#define HRS  296       // half-chunk row stride = 4*BS + 8 halves (148 words %32 == 20)
#define HALF (NB * HRS)   // 9472 halves = 18944 B per buffer
#define XS   168       // x/W1 LDS col stride, halves

typedef _Float16 fh8 __attribute__((ext_vector_type(8)));   // MFMA A/B frag (4 VGPRs)
typedef __attribute__((ext_vector_type(4))) float f32x4;    // MFMA C/D frag

__device__ __forceinline__ unsigned short f2h(float f) {
    return __half_as_ushort(__float2half(f));
}

struct Conn { int idx[12]; float w[12]; };   // 4 vertex-groups x 3 neighbors

// ---------------------------------------------------------------------------
// Fused prep kernel.
// Blocks 0..127: transpose Wg[o] -> W2 [S][o][kk] fp16 via LDS (both global
//   sides coalesced; LDS row stride 81 words kills the stride-80 conflict).
// Blocks 128..752: h = relu(x @ W1^T) -> fp16, 32 rows/block via MFMA.
// ---------------------------------------------------------------------------
__global__ __launch_bounds__(256) void prep_kernel(
    const float* __restrict__ Wg, const float* __restrict__ x,
    const float* __restrict__ W1, unsigned short* __restrict__ W2,
    unsigned short* __restrict__ hb) {
    __shared__ __align__(16) unsigned char smem[32256];
    const int tid = threadIdx.x;

    if (blockIdx.x < 128) {
        float* lds = (float*)smem;                 // 64*81 = 5184 words
        const int o = blockIdx.x;
        const float* src = Wg + o * KTOT;
        for (int t = tid; t < KTOT; t += 256) {    // t = h*80 + bin
            int h = t / 80, bin = t - h * 80;
            lds[h * 81 + bin] = src[t];
        }
        __syncthreads();
        for (int t = tid; t < KTOT; t += 256) {    // t = k = bin*64 + h
            W2[(t >> 5) * 4096 + o * 32 + (t & 31)] =
                f2h(lds[(t & 63) * 81 + (t >> 6)]);
        }
        return;
    }

    unsigned short* xs = (unsigned short*)smem;    // 32*168
    unsigned short* ws = xs + 32 * XS;             // 64*168
    const int n0 = (blockIdx.x - 128) * 32;

    for (int e = tid; e < 32 * INF; e += 256) {
        int r = e / INF, c = e - r * INF;
        xs[r * XS + c] = f2h(x[n0 * INF + e]);
    }
    for (int e = tid; e < 32 * 18; e += 256) {
        int r = e / 18, c = e - r * 18;
        xs[r * XS + 150 + c] = 0;
    }
    for (int e = tid; e < 64 * INF; e += 256) {
        int r = e / INF, c = e - r * INF;
        ws[r * XS + c] = f2h(W1[e]);
    }
    for (int e = tid; e < 64 * 18; e += 256) {
        int r = e / 18, c = e - r * 18;
        ws[r * XS + 150 + c] = 0;
    }
    __syncthreads();

    const int wv   = tid >> 6;
    const int lane = tid & 63;
    const int q    = lane >> 4;
    const int r16  = lane & 15;
    const int o0   = wv * 16;

    f32x4 acc0 = {0.f, 0.f, 0.f, 0.f};
    f32x4 acc1 = acc0;
    #pragma unroll
    for (int s = 0; s < 5; s++) {
        const int kb = s * 32 + q * 8;
        fh8 a0 = *(const fh8*)(xs + r16 * XS + kb);
        fh8 a1 = *(const fh8*)(xs + (16 + r16) * XS + kb);
        fh8 b  = *(const fh8*)(ws + (o0 + r16) * XS + kb);
        acc0 = __builtin_amdgcn_mfma_f32_16x16x32_f16(a0, b, acc0, 0, 0, 0);
        acc1 = __builtin_amdgcn_mfma_f32_16x16x32_f16(a1, b, acc1, 0, 0, 0);
    }
    #pragma unroll
    for (int r = 0; r < 4; r++) {
        float v0 = acc0[r] > 0.f ? acc0[r] : 0.f;
        float v1 = acc1[r] > 0.f ? acc1[r] : 0.f;
        hb[(n0 + q * 4 + r) * HH + o0 + r16]      = f2h(v0);
        hb[(n0 + 16 + q * 4 + r) * HH + o0 + r16] = f2h(v1);
    }
}

// ---------------------------------------------------------------------------
// Fused gather + fp16 MFMA + bias + L2 normalize, software-pipelined.
// 256 thr = 4 waves, 32 vertices/block. K split into 20 half-chunks of 4 bins
// (256 k each). Double-buffered pch; per iteration:
//   conn loads 2 iters ahead -> regs, hb gathers 1 iter ahead -> regs,
//   8 MFMA k-steps on current buffer, combine+ds_write to other buffer,
//   ONE barrier. Loads stay in flight across the MFMA phase.
// ---------------------------------------------------------------------------
__global__ __launch_bounds__(256, 2) void geo_kernel(
    const int*   __restrict__ conn_idx, const float* __restrict__ conn_w,
    const unsigned short* __restrict__ W2, const unsigned short* __restrict__ hb,
    const float* __restrict__ bg, float* __restrict__ out) {
    __shared__ __align__(16) unsigned short pch[2 * HALF];  // 37888 B
    __shared__ float rsq[NB];
    float* outbuf = (float*)pch;                 // 32*132*4 = 16896 B, aliased

    const int tid  = threadIdx.x;
    const int n0   = blockIdx.x * NB;
    const int wv   = tid >> 6;
    const int lane = tid & 63;
    const int q    = lane >> 4;
    const int r16  = lane & 15;
    const int j8   = tid & 7;                    // 16B segment of h row
    const int bb   = (tid >> 3) & 3;             // bin within half-chunk
    const int nb8  = tid >> 5;                   // vertex sub-row 0..7

    f32x4 acc00 = {0.f, 0.f, 0.f, 0.f};
    f32x4 acc01 = acc00, acc10 = acc00, acc11 = acc00;

    Conn cA, cB;
    fh8  hv[12];

    auto loadc = [&](int hc, Conn& c) {          // conn for half-chunk hc
        #pragma unroll
        for (int i = 0; i < 4; i++) {
            const int n = i * 8 + nb8;
            const int g = (n0 + n) * (PT * KK) + (hc * 4 + bb) * KK;
            c.idx[i * 3 + 0] = conn_idx[g];
            c.idx[i * 3 + 1] = conn_idx[g + 1];
            c.idx[i * 3 + 2] = conn_idx[g + 2];
            c.w[i * 3 + 0]   = conn_w[g];
            c.w[i * 3 + 1]   = conn_w[g + 1];
            c.w[i * 3 + 2]   = conn_w[g + 2];
        }
    };
    auto loadh = [&](const Conn& c) {            // gather h rows -> regs
        #pragma unroll
        for (int t = 0; t < 12; t++)
            hv[t] = *(const fh8*)(hb + c.idx[t] * HH + j8 * 8);
    };
    auto cwrite = [&](const Conn& c, unsigned short* buf) {  // combine + LDS
        #pragma unroll
        for (int i = 0; i < 4; i++) {
            const int n = i * 8 + nb8;
            _Float16 w0 = (_Float16)c.w[i * 3 + 0];
            _Float16 w1 = (_Float16)c.w[i * 3 + 1];
            _Float16 w2 = (_Float16)c.w[i * 3 + 2];
            fh8 W0 = {w0, w0, w0, w0, w0, w0, w0, w0};
            fh8 W1v = {w1, w1, w1, w1, w1, w1, w1, w1};
            fh8 W2v = {w2, w2, w2, w2, w2, w2, w2, w2};
            fh8 r = hv[i * 3] * W0 + hv[i * 3 + 1] * W1v + hv[i * 3 + 2] * W2v;
            *(fh8*)(buf + n * HRS + bb * BS + j8 * 8) = r;
        }
    };
    auto mfmaph = [&](const unsigned short* buf, int hc) {   // 8 k-steps
        #pragma unroll
        for (int s = 0; s < 8; s++) {
            const int S  = hc * 8 + s;
            const int ao = (s >> 1) * BS + (s & 1) * 32 + q * 8;
            fh8 a0 = *(const fh8*)(buf + r16 * HRS + ao);
            fh8 a1 = *(const fh8*)(buf + (16 + r16) * HRS + ao);
            fh8 b0 = *(const fh8*)(W2 + S * 4096 + (wv * 32 + r16) * 32 + q * 8);
            fh8 b1 = *(const fh8*)(W2 + S * 4096 + (wv * 32 + 16 + r16) * 32 + q * 8);
            acc00 = __builtin_amdgcn_mfma_f32_16x16x32_f16(a0, b0, acc00, 0, 0, 0);
            acc01 = __builtin_amdgcn_mfma_f32_16x16x32_f16(a0, b1, acc01, 0, 0, 0);
            acc10 = __builtin_amdgcn_mfma_f32_16x16x32_f16(a1, b0, acc10, 0, 0, 0);
            acc11 = __builtin_amdgcn_mfma_f32_16x16x32_f16(a1, b1, acc11, 0, 0, 0);
        }
    };

    // Prologue: conn[0]->cA, conn[1]->cB, gather+write half-chunk 0 into buf0
    loadc(0, cA);
    loadc(1, cB);
    loadh(cA);
    cwrite(cA, pch);
    __syncthreads();

    auto body = [&](int hc, Conn& use, Conn& fill) {
        if (hc + 2 < 20) loadc(hc + 2, fill);    // conn 2 ahead
        if (hc + 1 < 20) loadh(use);             // hb gathers 1 ahead (in flight
        mfmaph(&pch[(hc & 1) * HALF], hc);       //   across the MFMA phase)
        if (hc + 1 < 20) cwrite(use, &pch[((hc + 1) & 1) * HALF]);
        __syncthreads();
    };
    for (int hc = 0; hc < 20; hc += 2) {
        body(hc, cB, cA);
        body(hc + 1, cA, cB);
    }

    // Epilogue. D layout: row = q*4+reg (vertex in tile), col = r16 (o in tile)
    {
        const int o0 = wv * 32;
        #pragma unroll
        for (int r = 0; r < 4; r++) {
            outbuf[(q * 4 + r) * 132 + o0 + r16]           = acc00[r];
            outbuf[(q * 4 + r) * 132 + o0 + 16 + r16]      = acc01[r];
            outbuf[(16 + q * 4 + r) * 132 + o0 + r16]      = acc10[r];
            outbuf[(16 + q * 4 + r) * 132 + o0 + 16 + r16] = acc11[r];
        }
    }
    __syncthreads();
    {   // bias + row L2 norm
        int rr = tid >> 3, l = tid & 7;
        float s = 0.f;
        for (int o = l; o < 128; o += 8) {
            float v = outbuf[rr * 132 + o] + bg[o];
            s += v * v;
        }
        for (int off = 4; off; off >>= 1) s += __shfl_down(s, off, 8);
        if (l == 0) rsq[rr] = rsqrtf(s);
    }
    __syncthreads();
    #pragma unroll
    for (int i = 0; i < 16; i++) {
        int e = i * 256 + tid;
        int n = e >> 7, o = e & 127;
        out[(n0 + n) * OO + o] = (outbuf[n * 132 + o] + bg[o]) * rsq[n];
    }
}

// ---------------------------------------------------------------------------
extern "C" void kernel_launch(void* const* d_in, const int* in_sizes, int n_in,
                              void* d_out, int out_size, void* d_ws, size_t ws_size,
                              hipStream_t stream) {
    const float* x        = (const float*)d_in[0];
    const int*   conn_idx = (const int*)  d_in[1];
    const float* conn_w   = (const float*)d_in[2];
    const float* W1       = (const float*)d_in[3];
    const float* Wg       = (const float*)d_in[4];
    const float* bg       = (const float*)d_in[5];
    float*       out      = (float*)d_out;

    unsigned short* W2 = (unsigned short*)d_ws;            // 655360 fp16 (1.31 MB)
    unsigned short* hb = W2 + OO * KTOT;                   // 1,280,000 fp16 (2.56 MB)

    hipLaunchKernelGGL(prep_kernel, dim3(128 + NV / 32), dim3(256), 0, stream,
                       Wg, x, W1, W2, hb);
    hipLaunchKernelGGL(geo_kernel, dim3(NV / NB), dim3(256), 0, stream,
                       conn_idx, conn_w, W2, hb, bg, out);
}

// Round 6
// 188.605 us; speedup vs baseline: 1.1206x; 1.0361x over previous
//
#include <hip/hip_runtime.h>
#include <hip/hip_fp16.h>

// Problem constants
#define NV   20000
#define KK   3
#define INF  150
#define HH   64
#define OO   128
#define PT   80
#define KTOT 5120      // 80 bins * 64 h
#define NB   32        // vertices per geo block
#define BS2  72        // per-bin stride in pch, halves (64 + 8 pad)
#define RS2  152       // 2-bin row stride = 2*BS2 + 8 halves (76 words %32 == 12)
#define CHB  (NB * RS2)   // 4864 halves = 9728 B per buffer
#define XS   168       // x/W1 LDS col stride, halves

typedef _Float16 fh8 __attribute__((ext_vector_type(8)));   // MFMA A/B frag (4 VGPRs)
typedef __attribute__((ext_vector_type(4))) float f32x4;    // MFMA C/D frag

__device__ __forceinline__ unsigned short f2h(float f) {
    return __half_as_ushort(__float2half(f));
}
__device__ __forceinline__ float h2f(unsigned short u) {
    return __half2float(__ushort_as_half(u));
}

struct Conn { int idx[6]; float w[6]; };   // 2 vertex-groups x 3 neighbors

// ---------------------------------------------------------------------------
// Fused prep kernel.
// Blocks 0..127: transpose Wg[o] -> W2 [S][o][kk] fp16 via LDS.
// Blocks 128..752: h = relu(x @ W1^T) -> fp16, 32 rows/block via MFMA.
// ---------------------------------------------------------------------------
__global__ __launch_bounds__(256) void prep_kernel(
    const float* __restrict__ Wg, const float* __restrict__ x,
    const float* __restrict__ W1, unsigned short* __restrict__ W2,
    unsigned short* __restrict__ hb) {
    __shared__ __align__(16) unsigned char smem[32256];
    const int tid = threadIdx.x;

    if (blockIdx.x < 128) {
        float* lds = (float*)smem;                 // 64*81 words
        const int o = blockIdx.x;
        const float* src = Wg + o * KTOT;
        for (int t = tid; t < KTOT; t += 256) {    // t = h*80 + bin
            int h = t / 80, bin = t - h * 80;
            lds[h * 81 + bin] = src[t];
        }
        __syncthreads();
        for (int t = tid; t < KTOT; t += 256) {    // t = k = bin*64 + h
            W2[(t >> 5) * 4096 + o * 32 + (t & 31)] =
                f2h(lds[(t & 63) * 81 + (t >> 6)]);
        }
        return;
    }

    unsigned short* xs = (unsigned short*)smem;    // 32*168
    unsigned short* ws = xs + 32 * XS;             // 64*168
    const int n0 = (blockIdx.x - 128) * 32;

    for (int e = tid; e < 32 * INF; e += 256) {
        int r = e / INF, c = e - r * INF;
        xs[r * XS + c] = f2h(x[n0 * INF + e]);
    }
    for (int e = tid; e < 32 * 18; e += 256) {
        int r = e / 18, c = e - r * 18;
        xs[r * XS + 150 + c] = 0;
    }
    for (int e = tid; e < 64 * INF; e += 256) {
        int r = e / INF, c = e - r * INF;
        ws[r * XS + c] = f2h(W1[e]);
    }
    for (int e = tid; e < 64 * 18; e += 256) {
        int r = e / 18, c = e - r * 18;
        ws[r * XS + 150 + c] = 0;
    }
    __syncthreads();

    const int wv   = tid >> 6;
    const int lane = tid & 63;
    const int q    = lane >> 4;
    const int r16  = lane & 15;
    const int o0   = wv * 16;

    f32x4 acc0 = {0.f, 0.f, 0.f, 0.f};
    f32x4 acc1 = acc0;
    #pragma unroll
    for (int s = 0; s < 5; s++) {
        const int kb = s * 32 + q * 8;
        fh8 a0 = *(const fh8*)(xs + r16 * XS + kb);
        fh8 a1 = *(const fh8*)(xs + (16 + r16) * XS + kb);
        fh8 b  = *(const fh8*)(ws + (o0 + r16) * XS + kb);
        acc0 = __builtin_amdgcn_mfma_f32_16x16x32_f16(a0, b, acc0, 0, 0, 0);
        acc1 = __builtin_amdgcn_mfma_f32_16x16x32_f16(a1, b, acc1, 0, 0, 0);
    }
    #pragma unroll
    for (int r = 0; r < 4; r++) {
        float v0 = acc0[r] > 0.f ? acc0[r] : 0.f;
        float v1 = acc1[r] > 0.f ? acc1[r] : 0.f;
        hb[(n0 + q * 4 + r) * HH + o0 + r16]      = f2h(v0);
        hb[(n0 + 16 + q * 4 + r) * HH + o0 + r16] = f2h(v1);
    }
}

// ---------------------------------------------------------------------------
// Split-K geo kernel: grid 1250 = 625 n-blocks x 2 K-slices (40 bins each).
// 256 thr = 4 waves, 32 vertices. 20 sub-chunks of 2 bins (128 k each),
// double-buffered LDS (19.5 KB), 1 barrier per sub-chunk, register pipeline:
// conn 2 ahead, hb gathers 1 ahead.
// DETERMINISTIC partials (no atomics, no memset): slice 0 -> plain fp32
// stores into d_out (pure overwrite); slice 1 -> fp16 stores into ws part1.
// ---------------------------------------------------------------------------
__global__ __launch_bounds__(256, 4) void geo_kernel(
    const int*   __restrict__ conn_idx, const float* __restrict__ conn_w,
    const unsigned short* __restrict__ W2, const unsigned short* __restrict__ hb,
    float* __restrict__ out, unsigned short* __restrict__ part1) {
    __shared__ __align__(16) unsigned short pch[2 * CHB];  // 19456 B

    const int tid  = threadIdx.x;
    const int ks   = blockIdx.x & 1;             // K-slice
    const int n0   = (blockIdx.x >> 1) * NB;
    const int wv   = tid >> 6;
    const int lane = tid & 63;
    const int q    = lane >> 4;
    const int r16  = lane & 15;
    const int j8   = tid & 7;                    // 16B segment of h row
    const int bl   = (tid >> 3) & 1;             // bin within sub-chunk
    const int ng   = tid >> 4;                   // vertex sub-row 0..15
    const int bbase = ks * 40;                   // first bin of this K-slice
    const int Sbase = ks * 80;                   // first 32-k step

    f32x4 acc00 = {0.f, 0.f, 0.f, 0.f};
    f32x4 acc01 = acc00, acc10 = acc00, acc11 = acc00;

    Conn cA, cB;
    fh8  hv[6];

    auto loadc = [&](int cc, Conn& c) {          // conn for sub-chunk cc
        const int bin = bbase + cc * 2 + bl;
        #pragma unroll
        for (int i = 0; i < 2; i++) {
            const int g = (n0 + ng + i * 16) * (PT * KK) + bin * KK;
            c.idx[i * 3 + 0] = conn_idx[g];
            c.idx[i * 3 + 1] = conn_idx[g + 1];
            c.idx[i * 3 + 2] = conn_idx[g + 2];
            c.w[i * 3 + 0]   = conn_w[g];
            c.w[i * 3 + 1]   = conn_w[g + 1];
            c.w[i * 3 + 2]   = conn_w[g + 2];
        }
    };
    auto loadh = [&](const Conn& c) {            // gather h rows -> regs
        #pragma unroll
        for (int t = 0; t < 6; t++)
            hv[t] = *(const fh8*)(hb + c.idx[t] * HH + j8 * 8);
    };
    auto cwrite = [&](const Conn& c, unsigned short* buf) {  // combine + LDS
        #pragma unroll
        for (int i = 0; i < 2; i++) {
            const int n = ng + i * 16;
            _Float16 w0 = (_Float16)c.w[i * 3 + 0];
            _Float16 w1 = (_Float16)c.w[i * 3 + 1];
            _Float16 w2 = (_Float16)c.w[i * 3 + 2];
            fh8 W0 = {w0, w0, w0, w0, w0, w0, w0, w0};
            fh8 W1v = {w1, w1, w1, w1, w1, w1, w1, w1};
            fh8 W2v = {w2, w2, w2, w2, w2, w2, w2, w2};
            fh8 r = hv[i * 3] * W0 + hv[i * 3 + 1] * W1v + hv[i * 3 + 2] * W2v;
            *(fh8*)(buf + n * RS2 + bl * BS2 + j8 * 8) = r;
        }
    };
    auto mfmaph = [&](const unsigned short* buf, int cc) {   // 4 k-steps
        #pragma unroll
        for (int s = 0; s < 4; s++) {
            const int S  = Sbase + cc * 4 + s;
            const int ao = (s >> 1) * BS2 + (s & 1) * 32 + q * 8;
            fh8 a0 = *(const fh8*)(buf + r16 * RS2 + ao);
            fh8 a1 = *(const fh8*)(buf + (16 + r16) * RS2 + ao);
            fh8 b0 = *(const fh8*)(W2 + S * 4096 + (wv * 32 + r16) * 32 + q * 8);
            fh8 b1 = *(const fh8*)(W2 + S * 4096 + (wv * 32 + 16 + r16) * 32 + q * 8);
            acc00 = __builtin_amdgcn_mfma_f32_16x16x32_f16(a0, b0, acc00, 0, 0, 0);
            acc01 = __builtin_amdgcn_mfma_f32_16x16x32_f16(a0, b1, acc01, 0, 0, 0);
            acc10 = __builtin_amdgcn_mfma_f32_16x16x32_f16(a1, b0, acc10, 0, 0, 0);
            acc11 = __builtin_amdgcn_mfma_f32_16x16x32_f16(a1, b1, acc11, 0, 0, 0);
        }
    };

    // Prologue
    loadc(0, cA);
    loadc(1, cB);
    loadh(cA);
    cwrite(cA, pch);
    __syncthreads();

    auto body = [&](int cc, Conn& use, Conn& fill) {
        if (cc + 2 < 20) loadc(cc + 2, fill);    // conn 2 ahead
        if (cc + 1 < 20) loadh(use);             // gathers 1 ahead, in flight
        mfmaph(&pch[(cc & 1) * CHB], cc);        //   across the MFMA phase
        if (cc + 1 < 20) cwrite(use, &pch[((cc + 1) & 1) * CHB]);
        __syncthreads();
    };
    for (int cc = 0; cc < 20; cc += 2) {
        body(cc, cB, cA);
        body(cc + 1, cA, cB);
    }

    // Partial store. D layout: row = q*4+reg, col = r16. Exactly one writer
    // per element per stage -> deterministic, no read of prior contents.
    const int o0 = wv * 32;
    if (ks == 0) {
        #pragma unroll
        for (int r = 0; r < 4; r++) {
            out[(n0 + q * 4 + r) * OO + o0 + r16]           = acc00[r];
            out[(n0 + q * 4 + r) * OO + o0 + 16 + r16]      = acc01[r];
            out[(n0 + 16 + q * 4 + r) * OO + o0 + r16]      = acc10[r];
            out[(n0 + 16 + q * 4 + r) * OO + o0 + 16 + r16] = acc11[r];
        }
    } else {
        #pragma unroll
        for (int r = 0; r < 4; r++) {
            part1[(n0 + q * 4 + r) * OO + o0 + r16]           = f2h(acc00[r]);
            part1[(n0 + q * 4 + r) * OO + o0 + 16 + r16]      = f2h(acc01[r]);
            part1[(n0 + 16 + q * 4 + r) * OO + o0 + r16]      = f2h(acc10[r]);
            part1[(n0 + 16 + q * 4 + r) * OO + o0 + 16 + r16] = f2h(acc11[r]);
        }
    }
}

// ---------------------------------------------------------------------------
// Epilogue: v = part0(out) + part1 + bg; out = v * rsqrt(sum v^2) per row.
// 32 rows/block, 8 threads per row. Reads then fully overwrites d_out.
// ---------------------------------------------------------------------------
__global__ __launch_bounds__(256) void norm_kernel(
    float* __restrict__ out, const unsigned short* __restrict__ part1,
    const float* __restrict__ bg) {
    const int tid = threadIdx.x;
    const int n   = blockIdx.x * 32 + (tid >> 3);
    const int l   = tid & 7;
    float v[16];
    float s = 0.f;
    #pragma unroll
    for (int i = 0; i < 16; i++) {
        const int o = i * 8 + l;
        v[i] = out[n * OO + o] + h2f(part1[n * OO + o]) + bg[o];
        s += v[i] * v[i];
    }
    for (int off = 4; off; off >>= 1) s += __shfl_down(s, off, 8);
    const float r = rsqrtf(__shfl(s, 0, 8));
    #pragma unroll
    for (int i = 0; i < 16; i++)
        out[n * OO + i * 8 + l] = v[i] * r;
}

// ---------------------------------------------------------------------------
extern "C" void kernel_launch(void* const* d_in, const int* in_sizes, int n_in,
                              void* d_out, int out_size, void* d_ws, size_t ws_size,
                              hipStream_t stream) {
    const float* x        = (const float*)d_in[0];
    const int*   conn_idx = (const int*)  d_in[1];
    const float* conn_w   = (const float*)d_in[2];
    const float* W1       = (const float*)d_in[3];
    const float* Wg       = (const float*)d_in[4];
    const float* bg       = (const float*)d_in[5];
    float*       out      = (float*)d_out;

    unsigned short* W2    = (unsigned short*)d_ws;         // 655360 fp16 (1.31 MB)
    unsigned short* hb    = W2 + OO * KTOT;                // 1,280,000 fp16 (2.56 MB)
    unsigned short* part1 = hb + NV * HH;                  // 2,560,000 fp16 (5.12 MB)

    hipLaunchKernelGGL(prep_kernel, dim3(128 + NV / 32), dim3(256), 0, stream,
                       Wg, x, W1, W2, hb);
    hipLaunchKernelGGL(geo_kernel, dim3(2 * NV / NB), dim3(256), 0, stream,
                       conn_idx, conn_w, W2, hb, out, part1);
    hipLaunchKernelGGL(norm_kernel, dim3(NV / 32), dim3(256), 0, stream,
                       out, part1, bg);
}